// Round 12
// baseline (159.252 us; speedup 1.0000x reference)
//
#include <hip/hip_runtime.h>
#include <stdint.h>

typedef float f32x4 __attribute__((ext_vector_type(4)));
typedef short bf16x8 __attribute__((ext_vector_type(8)));
typedef uint32_t u32;

// d_ws layout (u32 units): fragment-ordered bf16 weights
#define W1_OFF 0u       // 16 kt * 4 nt  frags, 256 u32 each
#define W2_OFF 16384u   //  2 kt * 4 nt
#define W3_OFF 18432u   //  2 kt * 32 nt
#define W4_OFF 34816u   // 16 kt * 32 nt
#define WS_WEIGHTS_BYTES (165888u * 4u)

__device__ __forceinline__ u32 f2bf(float f) {
  u32 b = __builtin_bit_cast(u32, f);
  return (b + 0x7FFFu + ((b >> 16) & 1u)) >> 16;  // RNE bf16
}
__device__ __forceinline__ u32 pack2(float lo, float hi) {
  return f2bf(lo) | (f2bf(hi) << 16);
}
__device__ __forceinline__ bf16x8 ld_frag(const u32* p) {
  union { uint4 u; bf16x8 v; } t;
  t.u = *reinterpret_cast<const uint4*>(p);
  return t.v;
}
__device__ __forceinline__ f32x4 mfma16(bf16x8 a, bf16x8 b, f32x4 c) {
  return __builtin_amdgcn_mfma_f32_16x16x32_bf16(a, b, c, 0, 0, 0);
}
// fast tanh: 1 - 2/(e^{2x}+1); v_exp + v_rcp, branch-free. err ~1e-6 << bf16 ulp.
__device__ __forceinline__ float fast_tanh(float x) {
  float xc = fminf(15.f, fmaxf(-15.f, x));
  float e = __expf(2.f * xc);
  return 1.f - 2.f * __builtin_amdgcn_rcpf(e + 1.f);
}

// ---------------- prep: repack weights into fragment-ordered bf16 ----------------
// frag element j of lane l holds W[kt*32 + 4*(l>>4) + (j&3) + 16*(j>>2)][nt*16 + (l&15)]
__global__ void prep_kernel(const float* __restrict__ W1, const float* __restrict__ W2,
                            const float* __restrict__ W3, const float* __restrict__ W4,
                            u32* __restrict__ ws) {
  int t = blockIdx.x * 256 + threadIdx.x;
  if (t >= 648 * 64) return;
  int f = t >> 6, l = t & 63;
  const float* W; int N, NT, fi; u32 off;
  if (f < 64)       { W = W1; N = 64;  NT = 4;  fi = f;       off = W1_OFF; }
  else if (f < 72)  { W = W2; N = 64;  NT = 4;  fi = f - 64;  off = W2_OFF; }
  else if (f < 136) { W = W3; N = 512; NT = 32; fi = f - 72;  off = W3_OFF; }
  else              { W = W4; N = 512; NT = 32; fi = f - 136; off = W4_OFF; }
  int kt = fi / NT, nt = fi % NT;
  int g = l >> 4, i = l & 15;
  int n = nt * 16 + i;
  int kb = kt * 32 + 4 * g;
  u32 w0 = pack2(W[(size_t)(kb + 0) * N + n],  W[(size_t)(kb + 1) * N + n]);
  u32 w1 = pack2(W[(size_t)(kb + 2) * N + n],  W[(size_t)(kb + 3) * N + n]);
  u32 w2 = pack2(W[(size_t)(kb + 16) * N + n], W[(size_t)(kb + 17) * N + n]);
  u32 w3 = pack2(W[(size_t)(kb + 18) * N + n], W[(size_t)(kb + 19) * N + n]);
  *reinterpret_cast<uint4*>(ws + off + (u32)fi * 256u + (u32)l * 4u) = make_uint4(w0, w1, w2, w3);
}

// ---------------- mono5: mono4 + chunked GEMM4 with pipelined noise/stores -----------
// 1024 blocks x 1024 threads. Block owns 32 rows (2 m-subtiles) x 512 cols.
// Delta vs R11: GEMM4 split into 2 column-chunks (ntl); chunk-0 noise issues after
// barrier B (latency hidden under GEMM3); chunk-1 noise under chunk-0 K-loop; stores
// issue per-chunk so the store stream spans the whole GEMM4 phase and chunk-0's drain
// overlaps chunk-1 compute. acc 16->8 VGPR, nz 16->8 live: more prefetch headroom.
__global__ __launch_bounds__(1024, 8) void mono5_kernel(
    const float* __restrict__ x, const float* __restrict__ noise,
    const u32* __restrict__ ws,
    const float* __restrict__ b1, const float* __restrict__ b2,
    const float* __restrict__ b3, const float* __restrict__ b4,
    const float* __restrict__ omega, const float* __restrict__ Kp,
    const float* __restrict__ alphap, float* __restrict__ out) {
  __shared__ __align__(16) char lds[36864];
  uint4* red = reinterpret_cast<uint4*>(lds);          // [mt][ks][nt][lane] f32x4 (32 KB)
  uint4* fst = reinterpret_cast<uint4*>(lds);          // [mt][kt][lane] (32 KB, aliases red)
  uint4* pf  = reinterpret_cast<uint4*>(lds + 32768);  // [mt][kt2][lane] phase frags (4 KB)
  const int tid = threadIdx.x;
  const int wave = tid >> 6, l = tid & 63;
  const int g = l >> 4, i = l & 15;
  const int m0 = blockIdx.x * 32;
  const int c0 = wave * 32;

  // ---- GEMM1 (swapped, split over 8 waves): wave w -> subtile mt=w&1, kts 4*(w>>1)..+3
  if (wave < 8) {
    const int mt = wave & 1, ks = wave >> 1;
    f32x4 acc1T[4] = {};
#pragma unroll
    for (int kk = 0; kk < 4; ++kk) {
      const int kt = ks * 4 + kk;
      const float* xr = x + (size_t)(m0 + mt * 16 + i) * 512 + kt * 32 + 4 * g;
      const f32x4 a0 = __builtin_nontemporal_load(reinterpret_cast<const f32x4*>(xr));
      const f32x4 a1 = __builtin_nontemporal_load(reinterpret_cast<const f32x4*>(xr + 16));
      union { u32 u[4]; bf16x8 v; } xf;
      xf.u[0] = pack2(a0[0], a0[1]); xf.u[1] = pack2(a0[2], a0[3]);
      xf.u[2] = pack2(a1[0], a1[1]); xf.u[3] = pack2(a1[2], a1[3]);
#pragma unroll
      for (int nt = 0; nt < 4; ++nt)
        acc1T[nt] = mfma16(ld_frag(ws + W1_OFF + (u32)(kt * 4 + nt) * 256u + (u32)l * 4u),
                           xf.v, acc1T[nt]);
    }
#pragma unroll
    for (int nt = 0; nt < 4; ++nt)
      red[((mt * 4 + ks) * 4 + nt) * 64 + l] = __builtin_bit_cast(uint4, acc1T[nt]);
  }
  __syncthreads();  // A: partials visible

  // ---- front: wave 0 -> subtile 0, wave 1 -> subtile 1 (parallel SIMDs)
  if (wave < 2) {
    const int mt = wave;
    f32x4 acc1T[4];
#pragma unroll
    for (int nt = 0; nt < 4; ++nt) {
      f32x4 s = {};
#pragma unroll
      for (int ks = 0; ks < 4; ++ks)
        s += __builtin_bit_cast(f32x4, red[((mt * 4 + ks) * 4 + nt) * 64 + l]);
      acc1T[nt] = s;
    }
    bf16x8 hfrag[2];
#pragma unroll
    for (int kt2 = 0; kt2 < 2; ++kt2) {
      union { u32 u[4]; bf16x8 v; } t;
#pragma unroll
      for (int q = 0; q < 2; ++q) {
        int nt = 2 * kt2 + q;
        int nb = 16 * nt + 4 * g;
        float v0 = fast_tanh(acc1T[nt][0] + b1[nb + 0]);
        float v1 = fast_tanh(acc1T[nt][1] + b1[nb + 1]);
        float v2 = fast_tanh(acc1T[nt][2] + b1[nb + 2]);
        float v3 = fast_tanh(acc1T[nt][3] + b1[nb + 3]);
        t.u[2 * q + 0] = pack2(v0, v1);
        t.u[2 * q + 1] = pack2(v2, v3);
      }
      hfrag[kt2] = t.v;
    }
    f32x4 acc2T[4] = {};
#pragma unroll
    for (int kt2 = 0; kt2 < 2; ++kt2)
#pragma unroll
      for (int ot = 0; ot < 4; ++ot)
        acc2T[ot] = mfma16(ld_frag(ws + W2_OFF + (u32)(kt2 * 4 + ot) * 256u + (u32)l * 4u),
                           hfrag[kt2], acc2T[ot]);
    float ph[4][4], om[4][4];
    const float Kc = Kp[0];
#pragma unroll
    for (int ot = 0; ot < 4; ++ot) {
      int ob = 16 * ot + 4 * g;
#pragma unroll
      for (int r = 0; r < 4; ++r) {
        ph[ot][r] = acc2T[ot][r] + b2[ob + r];
        om[ot][r] = omega[ob + r];
      }
    }
#pragma unroll
    for (int s = 0; s < 10; ++s) {
      float rs = 0.f;
      float cs[4][4];
#pragma unroll
      for (int ot = 0; ot < 4; ++ot)
#pragma unroll
        for (int r = 0; r < 4; ++r) {
          float sv, cv;
          __sincosf(ph[ot][r], &sv, &cv);
          rs += sv;
          cs[ot][r] = cv;
        }
      rs += __shfl_xor(rs, 16);
      rs += __shfl_xor(rs, 32);
      float sc = 0.01f * Kc * rs * 0.015625f;
#pragma unroll
      for (int ot = 0; ot < 4; ++ot)
#pragma unroll
        for (int r = 0; r < 4; ++r)
          ph[ot][r] += 0.01f * om[ot][r] + sc * cs[ot][r];
    }
#pragma unroll
    for (int kt2 = 0; kt2 < 2; ++kt2) {
      union { u32 u[4]; uint4 u4; } t;
#pragma unroll
      for (int q = 0; q < 2; ++q) {
        int nt = 2 * kt2 + q;
        t.u[2 * q + 0] = pack2(ph[nt][0], ph[nt][1]);
        t.u[2 * q + 1] = pack2(ph[nt][2], ph[nt][3]);
      }
      pf[mt * 128 + kt2 * 64 + l] = t.u4;
    }
  }
  __syncthreads();  // B: phase frags visible; red dead (only front waves read it)

  // ---- noise chunk 0 prefetch: latency hides under GEMM3
  const int colc0 = c0 + i;
  float nz0[8];
#pragma unroll
  for (int st = 0; st < 2; ++st)
#pragma unroll
    for (int r = 0; r < 4; ++r)
      nz0[st * 4 + r] = __builtin_nontemporal_load(
          noise + (size_t)(m0 + st * 16 + 4 * g + r) * 512 + colc0);

  // ---- GEMM3 (swapped, all 16 waves): wave -> mt = w&1, c = w>>1 (nt 4c..4c+3)
  {
    const int mt = wave & 1, c = wave >> 1;
    bf16x8 pfrag[2];
#pragma unroll
    for (int kt2 = 0; kt2 < 2; ++kt2)
      pfrag[kt2] = __builtin_bit_cast(bf16x8, pf[mt * 128 + kt2 * 64 + l]);
    f32x4 a3[4] = {};
#pragma unroll
    for (int kt2 = 0; kt2 < 2; ++kt2)
#pragma unroll
      for (int nl = 0; nl < 4; ++nl)
        a3[nl] = mfma16(ld_frag(ws + W3_OFF + (u32)(kt2 * 32 + c * 4 + nl) * 256u + (u32)l * 4u),
                        pfrag[kt2], a3[nl]);
#pragma unroll
    for (int q = 0; q < 2; ++q) {
      union { u32 u[4]; uint4 u4; } t;
#pragma unroll
      for (int p = 0; p < 2; ++p) {
        int nl = 2 * q + p;
        int nb = 16 * (4 * c + nl) + 4 * g;
        float v0 = a3[nl][0] + b3[nb + 0]; v0 = v0 > 0.f ? v0 : 0.f;
        float v1 = a3[nl][1] + b3[nb + 1]; v1 = v1 > 0.f ? v1 : 0.f;
        float v2 = a3[nl][2] + b3[nb + 2]; v2 = v2 > 0.f ? v2 : 0.f;
        float v3 = a3[nl][3] + b3[nb + 3]; v3 = v3 > 0.f ? v3 : 0.f;
        t.u[2 * p + 0] = pack2(v0, v1);
        t.u[2 * p + 1] = pack2(v2, v3);
      }
      fst[mt * 1024 + (2 * c + q) * 64 + l] = t.u4;  // overwrites red (dead)
    }
  }
  __syncthreads();  // C: f-frags visible

  const float alpha = alphap[0];

  // ---- GEMM4 chunk 0 (cols c0..c0+15): K-loop, then stores (drain overlaps chunk 1)
  {
    f32x4 accA = {}, accB = {};
#pragma unroll
    for (int kt = 0; kt < 16; ++kt) {
      union { uint4 u; bf16x8 v; } aA, aB;
      aA.u = fst[kt * 64 + l];
      aB.u = fst[1024 + kt * 64 + l];
      bf16x8 bf = ld_frag(ws + W4_OFF + (u32)(kt * 32 + wave * 2) * 256u + (u32)l * 4u);
      accA = mfma16(aA.v, bf, accA);
      accB = mfma16(aB.v, bf, accB);
    }
    float fmv = __sinf(alpha * (float)colc0);
    float bbv = b4[colc0];
#pragma unroll
    for (int r = 0; r < 4; ++r) {
      size_t idxA = (size_t)(m0 + 4 * g + r) * 512 + colc0;
      size_t idxB = (size_t)(m0 + 16 + 4 * g + r) * 512 + colc0;
      float imA = nz0[r] * fmv;
      float imB = nz0[4 + r] * fmv;
      f32x4 oA = {accA[r] + bbv, imA, imA, imA};
      f32x4 oB = {accB[r] + bbv, imB, imB, imB};
      __builtin_nontemporal_store(oA, reinterpret_cast<f32x4*>(out + idxA * 4));
      __builtin_nontemporal_store(oB, reinterpret_cast<f32x4*>(out + idxB * 4));
    }
  }

  // ---- GEMM4 chunk 1 (cols c0+16..c0+31): noise prefetch first, K-loop, stores
  {
    const int colc1 = colc0 + 16;
    float nz1[8];
#pragma unroll
    for (int st = 0; st < 2; ++st)
#pragma unroll
      for (int r = 0; r < 4; ++r)
        nz1[st * 4 + r] = __builtin_nontemporal_load(
            noise + (size_t)(m0 + st * 16 + 4 * g + r) * 512 + colc1);
    f32x4 accA = {}, accB = {};
#pragma unroll
    for (int kt = 0; kt < 16; ++kt) {
      union { uint4 u; bf16x8 v; } aA, aB;
      aA.u = fst[kt * 64 + l];
      aB.u = fst[1024 + kt * 64 + l];
      bf16x8 bf = ld_frag(ws + W4_OFF + (u32)(kt * 32 + wave * 2 + 1) * 256u + (u32)l * 4u);
      accA = mfma16(aA.v, bf, accA);
      accB = mfma16(aB.v, bf, accB);
    }
    float fmv = __sinf(alpha * (float)colc1);
    float bbv = b4[colc1];
#pragma unroll
    for (int r = 0; r < 4; ++r) {
      size_t idxA = (size_t)(m0 + 4 * g + r) * 512 + colc1;
      size_t idxB = (size_t)(m0 + 16 + 4 * g + r) * 512 + colc1;
      float imA = nz1[r] * fmv;
      float imB = nz1[4 + r] * fmv;
      f32x4 oA = {accA[r] + bbv, imA, imA, imA};
      f32x4 oB = {accB[r] + bbv, imB, imB, imB};
      __builtin_nontemporal_store(oA, reinterpret_cast<f32x4*>(out + idxA * 4));
      __builtin_nontemporal_store(oB, reinterpret_cast<f32x4*>(out + idxB * 4));
    }
  }
}

extern "C" void kernel_launch(void* const* d_in, const int* in_sizes, int n_in,
                              void* d_out, int out_size, void* d_ws, size_t ws_size,
                              hipStream_t stream) {
  if (ws_size < WS_WEIGHTS_BYTES) return;  // need 648 KB fragment-ordered weights
  const float* x      = (const float*)d_in[0];
  const float* noise  = (const float*)d_in[1];
  const float* W1     = (const float*)d_in[2];
  const float* b1     = (const float*)d_in[3];
  const float* W2     = (const float*)d_in[4];
  const float* b2     = (const float*)d_in[5];
  const float* W3     = (const float*)d_in[6];
  const float* b3     = (const float*)d_in[7];
  const float* W4     = (const float*)d_in[8];
  const float* b4     = (const float*)d_in[9];
  const float* omega  = (const float*)d_in[10];
  const float* Kp     = (const float*)d_in[11];
  const float* alphap = (const float*)d_in[12];
  u32* ws = (u32*)d_ws;
  prep_kernel<<<162, 256, 0, stream>>>(W1, W2, W3, W4, ws);
  mono5_kernel<<<1024, 1024, 0, stream>>>(x, noise, ws, b1, b2, b3, b4,
                                          omega, Kp, alphap, (float*)d_out);
}

// Round 13
// 106.147 us; speedup vs baseline: 1.5003x; 1.5003x over previous
//
#include <hip/hip_runtime.h>
#include <stdint.h>

typedef float f32x4 __attribute__((ext_vector_type(4)));
typedef short bf16x8 __attribute__((ext_vector_type(8)));
typedef uint32_t u32;

// d_ws layout (u32 units): fragment-ordered bf16 weights
#define W1_OFF 0u       // 16 kt * 4 nt  frags, 256 u32 each
#define W2_OFF 16384u   //  2 kt * 4 nt
#define W3_OFF 18432u   //  2 kt * 32 nt
#define W4_OFF 34816u   // 16 kt * 32 nt
#define WS_WEIGHTS_BYTES (165888u * 4u)

__device__ __forceinline__ u32 f2bf(float f) {
  u32 b = __builtin_bit_cast(u32, f);
  return (b + 0x7FFFu + ((b >> 16) & 1u)) >> 16;  // RNE bf16
}
__device__ __forceinline__ u32 pack2(float lo, float hi) {
  return f2bf(lo) | (f2bf(hi) << 16);
}
__device__ __forceinline__ bf16x8 ld_frag(const u32* p) {
  union { uint4 u; bf16x8 v; } t;
  t.u = *reinterpret_cast<const uint4*>(p);
  return t.v;
}
__device__ __forceinline__ f32x4 mfma16(bf16x8 a, bf16x8 b, f32x4 c) {
  return __builtin_amdgcn_mfma_f32_16x16x32_bf16(a, b, c, 0, 0, 0);
}
// fast tanh: 1 - 2/(e^{2x}+1); v_exp + v_rcp, branch-free. err ~1e-6 << bf16 ulp.
__device__ __forceinline__ float fast_tanh(float x) {
  float xc = fminf(15.f, fmaxf(-15.f, x));
  float e = __expf(2.f * xc);
  return 1.f - 2.f * __builtin_amdgcn_rcpf(e + 1.f);
}

// ---------------- prep: repack weights into fragment-ordered bf16 ----------------
// frag element j of lane l holds W[kt*32 + 4*(l>>4) + (j&3) + 16*(j>>2)][nt*16 + (l&15)]
__global__ void prep_kernel(const float* __restrict__ W1, const float* __restrict__ W2,
                            const float* __restrict__ W3, const float* __restrict__ W4,
                            u32* __restrict__ ws) {
  int t = blockIdx.x * 256 + threadIdx.x;
  if (t >= 648 * 64) return;
  int f = t >> 6, l = t & 63;
  const float* W; int N, NT, fi; u32 off;
  if (f < 64)       { W = W1; N = 64;  NT = 4;  fi = f;       off = W1_OFF; }
  else if (f < 72)  { W = W2; N = 64;  NT = 4;  fi = f - 64;  off = W2_OFF; }
  else if (f < 136) { W = W3; N = 512; NT = 32; fi = f - 72;  off = W3_OFF; }
  else              { W = W4; N = 512; NT = 32; fi = f - 136; off = W4_OFF; }
  int kt = fi / NT, nt = fi % NT;
  int g = l >> 4, i = l & 15;
  int n = nt * 16 + i;
  int kb = kt * 32 + 4 * g;
  u32 w0 = pack2(W[(size_t)(kb + 0) * N + n],  W[(size_t)(kb + 1) * N + n]);
  u32 w1 = pack2(W[(size_t)(kb + 2) * N + n],  W[(size_t)(kb + 3) * N + n]);
  u32 w2 = pack2(W[(size_t)(kb + 16) * N + n], W[(size_t)(kb + 17) * N + n]);
  u32 w3 = pack2(W[(size_t)(kb + 18) * N + n], W[(size_t)(kb + 19) * N + n]);
  *reinterpret_cast<uint4*>(ws + off + (u32)fi * 256u + (u32)l * 4u) = make_uint4(w0, w1, w2, w3);
}

// ---------------- mono6: mono4 (R11 champion) + early noise prefetch -----------------
// 1024 blocks x 1024 threads. Block owns 32 rows (2 m-subtiles) x 512 cols.
// Single delta vs R11: the 16 noise loads issue right after barrier B (latency hides
// under GEMM3 + GEMM4 K-loop) instead of in the terminal epilogue burst. Normal
// (cached) loads — nt scalar reads touch 64B half-lines and risk refetch. K-loop,
// accumulators, barriers identical to R11 (register profile matches R5's clean 64-VGPR
// compile: nz[16] + acc[16] live through the K-loop).
__global__ __launch_bounds__(1024, 8) void mono6_kernel(
    const float* __restrict__ x, const float* __restrict__ noise,
    const u32* __restrict__ ws,
    const float* __restrict__ b1, const float* __restrict__ b2,
    const float* __restrict__ b3, const float* __restrict__ b4,
    const float* __restrict__ omega, const float* __restrict__ Kp,
    const float* __restrict__ alphap, float* __restrict__ out) {
  __shared__ __align__(16) char lds[36864];
  uint4* red = reinterpret_cast<uint4*>(lds);          // [mt][ks][nt][lane] f32x4 (32 KB)
  uint4* fst = reinterpret_cast<uint4*>(lds);          // [mt][kt][lane] (32 KB, aliases red)
  uint4* pf  = reinterpret_cast<uint4*>(lds + 32768);  // [mt][kt2][lane] phase frags (4 KB)
  const int tid = threadIdx.x;
  const int wave = tid >> 6, l = tid & 63;
  const int g = l >> 4, i = l & 15;
  const int m0 = blockIdx.x * 32;
  const int c0 = wave * 32;

  // ---- GEMM1 (swapped, split over 8 waves): wave w -> subtile mt=w&1, kts 4*(w>>1)..+3
  if (wave < 8) {
    const int mt = wave & 1, ks = wave >> 1;
    f32x4 acc1T[4] = {};
#pragma unroll
    for (int kk = 0; kk < 4; ++kk) {
      const int kt = ks * 4 + kk;
      const float* xr = x + (size_t)(m0 + mt * 16 + i) * 512 + kt * 32 + 4 * g;
      const f32x4 a0 = __builtin_nontemporal_load(reinterpret_cast<const f32x4*>(xr));
      const f32x4 a1 = __builtin_nontemporal_load(reinterpret_cast<const f32x4*>(xr + 16));
      union { u32 u[4]; bf16x8 v; } xf;
      xf.u[0] = pack2(a0[0], a0[1]); xf.u[1] = pack2(a0[2], a0[3]);
      xf.u[2] = pack2(a1[0], a1[1]); xf.u[3] = pack2(a1[2], a1[3]);
#pragma unroll
      for (int nt = 0; nt < 4; ++nt)
        acc1T[nt] = mfma16(ld_frag(ws + W1_OFF + (u32)(kt * 4 + nt) * 256u + (u32)l * 4u),
                           xf.v, acc1T[nt]);
    }
#pragma unroll
    for (int nt = 0; nt < 4; ++nt)
      red[((mt * 4 + ks) * 4 + nt) * 64 + l] = __builtin_bit_cast(uint4, acc1T[nt]);
  }
  __syncthreads();  // A: partials visible

  // ---- front: wave 0 -> subtile 0, wave 1 -> subtile 1 (parallel SIMDs)
  if (wave < 2) {
    const int mt = wave;
    f32x4 acc1T[4];
#pragma unroll
    for (int nt = 0; nt < 4; ++nt) {
      f32x4 s = {};
#pragma unroll
      for (int ks = 0; ks < 4; ++ks)
        s += __builtin_bit_cast(f32x4, red[((mt * 4 + ks) * 4 + nt) * 64 + l]);
      acc1T[nt] = s;
    }
    bf16x8 hfrag[2];
#pragma unroll
    for (int kt2 = 0; kt2 < 2; ++kt2) {
      union { u32 u[4]; bf16x8 v; } t;
#pragma unroll
      for (int q = 0; q < 2; ++q) {
        int nt = 2 * kt2 + q;
        int nb = 16 * nt + 4 * g;
        float v0 = fast_tanh(acc1T[nt][0] + b1[nb + 0]);
        float v1 = fast_tanh(acc1T[nt][1] + b1[nb + 1]);
        float v2 = fast_tanh(acc1T[nt][2] + b1[nb + 2]);
        float v3 = fast_tanh(acc1T[nt][3] + b1[nb + 3]);
        t.u[2 * q + 0] = pack2(v0, v1);
        t.u[2 * q + 1] = pack2(v2, v3);
      }
      hfrag[kt2] = t.v;
    }
    f32x4 acc2T[4] = {};
#pragma unroll
    for (int kt2 = 0; kt2 < 2; ++kt2)
#pragma unroll
      for (int ot = 0; ot < 4; ++ot)
        acc2T[ot] = mfma16(ld_frag(ws + W2_OFF + (u32)(kt2 * 4 + ot) * 256u + (u32)l * 4u),
                           hfrag[kt2], acc2T[ot]);
    float ph[4][4], om[4][4];
    const float Kc = Kp[0];
#pragma unroll
    for (int ot = 0; ot < 4; ++ot) {
      int ob = 16 * ot + 4 * g;
#pragma unroll
      for (int r = 0; r < 4; ++r) {
        ph[ot][r] = acc2T[ot][r] + b2[ob + r];
        om[ot][r] = omega[ob + r];
      }
    }
#pragma unroll
    for (int s = 0; s < 10; ++s) {
      float rs = 0.f;
      float cs[4][4];
#pragma unroll
      for (int ot = 0; ot < 4; ++ot)
#pragma unroll
        for (int r = 0; r < 4; ++r) {
          float sv, cv;
          __sincosf(ph[ot][r], &sv, &cv);
          rs += sv;
          cs[ot][r] = cv;
        }
      rs += __shfl_xor(rs, 16);
      rs += __shfl_xor(rs, 32);
      float sc = 0.01f * Kc * rs * 0.015625f;
#pragma unroll
      for (int ot = 0; ot < 4; ++ot)
#pragma unroll
        for (int r = 0; r < 4; ++r)
          ph[ot][r] += 0.01f * om[ot][r] + sc * cs[ot][r];
    }
#pragma unroll
    for (int kt2 = 0; kt2 < 2; ++kt2) {
      union { u32 u[4]; uint4 u4; } t;
#pragma unroll
      for (int q = 0; q < 2; ++q) {
        int nt = 2 * kt2 + q;
        t.u[2 * q + 0] = pack2(ph[nt][0], ph[nt][1]);
        t.u[2 * q + 1] = pack2(ph[nt][2], ph[nt][3]);
      }
      pf[mt * 128 + kt2 * 64 + l] = t.u4;
    }
  }
  __syncthreads();  // B: phase frags visible; red dead (only front waves read it)

  // ---- noise prefetch (moved up from epilogue): latency hides under GEMM3 + K-loop
  float nz[16];
#pragma unroll
  for (int ntl = 0; ntl < 2; ++ntl) {
    int col = c0 + ntl * 16 + i;
#pragma unroll
    for (int st = 0; st < 2; ++st)
#pragma unroll
      for (int r = 0; r < 4; ++r)
        nz[ntl * 8 + st * 4 + r] =
            noise[(size_t)(m0 + st * 16 + 4 * g + r) * 512 + col];
  }

  // ---- GEMM3 (swapped, all 16 waves): wave -> mt = w&1, c = w>>1 (nt 4c..4c+3)
  {
    const int mt = wave & 1, c = wave >> 1;
    bf16x8 pfrag[2];
#pragma unroll
    for (int kt2 = 0; kt2 < 2; ++kt2)
      pfrag[kt2] = __builtin_bit_cast(bf16x8, pf[mt * 128 + kt2 * 64 + l]);
    f32x4 a3[4] = {};
#pragma unroll
    for (int kt2 = 0; kt2 < 2; ++kt2)
#pragma unroll
      for (int nl = 0; nl < 4; ++nl)
        a3[nl] = mfma16(ld_frag(ws + W3_OFF + (u32)(kt2 * 32 + c * 4 + nl) * 256u + (u32)l * 4u),
                        pfrag[kt2], a3[nl]);
#pragma unroll
    for (int q = 0; q < 2; ++q) {
      union { u32 u[4]; uint4 u4; } t;
#pragma unroll
      for (int p = 0; p < 2; ++p) {
        int nl = 2 * q + p;
        int nb = 16 * (4 * c + nl) + 4 * g;
        float v0 = a3[nl][0] + b3[nb + 0]; v0 = v0 > 0.f ? v0 : 0.f;
        float v1 = a3[nl][1] + b3[nb + 1]; v1 = v1 > 0.f ? v1 : 0.f;
        float v2 = a3[nl][2] + b3[nb + 2]; v2 = v2 > 0.f ? v2 : 0.f;
        float v3 = a3[nl][3] + b3[nb + 3]; v3 = v3 > 0.f ? v3 : 0.f;
        t.u[2 * p + 0] = pack2(v0, v1);
        t.u[2 * p + 1] = pack2(v2, v3);
      }
      fst[mt * 1024 + (2 * c + q) * 64 + l] = t.u4;  // overwrites red (dead)
    }
  }
  __syncthreads();  // C: f-frags visible

  // ---- GEMM4: wave owns 32 cols x both subtiles; B-frag reused across subtiles
  f32x4 accA[2] = {}, accB[2] = {};
#pragma unroll
  for (int kt = 0; kt < 16; ++kt) {
    union { uint4 u; bf16x8 v; } aA, aB;
    aA.u = fst[kt * 64 + l];
    aB.u = fst[1024 + kt * 64 + l];
#pragma unroll
    for (int ntl = 0; ntl < 2; ++ntl) {
      bf16x8 bf = ld_frag(ws + W4_OFF + (u32)(kt * 32 + wave * 2 + ntl) * 256u + (u32)l * 4u);
      accA[ntl] = mfma16(aA.v, bf, accA[ntl]);
      accB[ntl] = mfma16(aB.v, bf, accB[ntl]);
    }
  }

  // ---- epilogue: pure FMA + nt coalesced f32x4 stores (noise already in registers)
  const float alpha = alphap[0];
#pragma unroll
  for (int ntl = 0; ntl < 2; ++ntl) {
    int col = c0 + ntl * 16 + i;
    float fmv = __sinf(alpha * (float)col);
    float bbv = b4[col];
#pragma unroll
    for (int r = 0; r < 4; ++r) {
      size_t idxA = (size_t)(m0 + 4 * g + r) * 512 + col;
      size_t idxB = (size_t)(m0 + 16 + 4 * g + r) * 512 + col;
      float imA = nz[ntl * 8 + r] * fmv;
      float imB = nz[ntl * 8 + 4 + r] * fmv;
      f32x4 oA = {accA[ntl][r] + bbv, imA, imA, imA};
      f32x4 oB = {accB[ntl][r] + bbv, imB, imB, imB};
      __builtin_nontemporal_store(oA, reinterpret_cast<f32x4*>(out + idxA * 4));
      __builtin_nontemporal_store(oB, reinterpret_cast<f32x4*>(out + idxB * 4));
    }
  }
}

extern "C" void kernel_launch(void* const* d_in, const int* in_sizes, int n_in,
                              void* d_out, int out_size, void* d_ws, size_t ws_size,
                              hipStream_t stream) {
  if (ws_size < WS_WEIGHTS_BYTES) return;  // need 648 KB fragment-ordered weights
  const float* x      = (const float*)d_in[0];
  const float* noise  = (const float*)d_in[1];
  const float* W1     = (const float*)d_in[2];
  const float* b1     = (const float*)d_in[3];
  const float* W2     = (const float*)d_in[4];
  const float* b2     = (const float*)d_in[5];
  const float* W3     = (const float*)d_in[6];
  const float* b3     = (const float*)d_in[7];
  const float* W4     = (const float*)d_in[8];
  const float* b4     = (const float*)d_in[9];
  const float* omega  = (const float*)d_in[10];
  const float* Kp     = (const float*)d_in[11];
  const float* alphap = (const float*)d_in[12];
  u32* ws = (u32*)d_ws;
  prep_kernel<<<162, 256, 0, stream>>>(W1, W2, W3, W4, ws);
  mono6_kernel<<<1024, 1024, 0, stream>>>(x, noise, ws, b1, b2, b3, b4,
                                          omega, Kp, alphap, (float*)d_out);
}